// Round 6
// baseline (161.571 us; speedup 1.0000x reference)
//
#include <hip/hip_runtime.h>
#include <hip/hip_bf16.h>

typedef __attribute__((ext_vector_type(8))) short short8;
typedef __attribute__((ext_vector_type(4))) float floatx4;
typedef __attribute__((ext_vector_type(4))) unsigned int uint4v;

#define NROW 148
#define ROWB 16384                       // 4 g * 32 ch * 128B strips
#define BB   ((size_t)NROW*ROWB)         // 2,424,832 B per batch
#define COPYB ((size_t)8*BB)             // 19.4 MB per parity copy; 2 copies = 38.8 MB

__device__ __forceinline__ unsigned short f2b(float f){
  unsigned int u = __float_as_uint(f);
  unsigned int r = (u + 0x7fffu + ((u >> 16) & 1u)) >> 16;  // RNE
  return (unsigned short)r;
}

// ---------------- Kernel 1: standardize + strip-interleaved pad ----------------
// pad[rA][b][yy][g][c][128B]: byte w of strip = xs[(yy-10)%128][(32g + w/2 - rA)%128]
// (64 consecutive x per channel per strip: 32 useful + 32 halo, line-aligned)
__global__ __launch_bounds__(256) void k_std(const float* __restrict__ x,
                                             unsigned char* __restrict__ pad){
  int bid = blockIdx.x;
  int b = bid >> 5, c = bid & 31;
  int t = threadIdx.x;
  const float* xc = x + ((size_t)(b*32 + c) << 14);
  float s = 0.f, ss = 0.f;
  #pragma unroll 4
  for (int k = 0; k < 64; ++k){
    float v = xc[t + (k << 8)];
    s += v; ss += v*v;
  }
  #pragma unroll
  for (int m = 32; m >= 1; m >>= 1){
    s  += __shfl_xor(s, m);
    ss += __shfl_xor(ss, m);
  }
  __shared__ float rs[4], rss[4], sc[2];
  int wv = t >> 6, l = t & 63;
  if (l == 0){ rs[wv] = s; rss[wv] = ss; }
  __syncthreads();
  if (t == 0){
    float S  = rs[0]+rs[1]+rs[2]+rs[3];
    float SS = rss[0]+rss[1]+rss[2]+rss[3];
    float mean = S * (1.f/16384.f);
    float var  = (SS - S*mean) * (1.f/16383.f);   // ddof=1
    float sd = sqrtf(fmaxf(var, 0.f));
    sc[0] = mean;
    sc[1] = (sd < 1e-9f) ? 0.f : 1.f/(sd*128.f);  // 1/(std*sqrt(16384))
  }
  __syncthreads();
  float mean = sc[0], scale = sc[1];
  // chunk writers: lane l -> (rA, g, kc); 16B chunk = elements 32g+8kc-rA+e
  int rA = l >> 5, u = l & 31, g = u >> 3, kc = u & 7;
  unsigned char* pb = pad + (size_t)rA*COPYB + (size_t)b*BB
                    + (unsigned)(g*4096 + c*128 + kc*16);
  int E2 = 16*g + 4*kc - rA;               // first source dword (may be -1 -> wraps)
  for (int it = 0; it < 37; ++it){
    int yy = wv*37 + it;                   // 4 waves x 37 rows = 148
    int sy = (yy + 118) & 127;             // (yy-10) mod 128
    unsigned int d0w = 0, d1w = 0;
    if (l < 32){
      const float4* src = (const float4*)(xc + (sy << 7));
      float4 v = src[l];                   // elements 4l..4l+3
      d0w = (unsigned)f2b((v.x - mean)*scale) | ((unsigned)f2b((v.y - mean)*scale) << 16);
      d1w = (unsigned)f2b((v.z - mean)*scale) | ((unsigned)f2b((v.w - mean)*scale) << 16);
    }
    unsigned int vv[5];
    #pragma unroll
    for (int k = 0; k < 5; ++k){
      int D = (E2 + k) & 63;               // source row dword index (64 dwords/row)
      unsigned int lo = (unsigned)__shfl((int)d0w, D >> 1);
      unsigned int hi = (unsigned)__shfl((int)d1w, D >> 1);
      vv[k] = (D & 1) ? hi : lo;
    }
    unsigned int o0, o1, o2, o3;
    if (rA){
      o0 = (vv[0]>>16)|(vv[1]<<16); o1 = (vv[1]>>16)|(vv[2]<<16);
      o2 = (vv[2]>>16)|(vv[3]<<16); o3 = (vv[3]>>16)|(vv[4]<<16);
    } else { o0 = vv[0]; o1 = vv[1]; o2 = vv[2]; o3 = vv[3]; }
    uint4v ov = {o0, o1, o2, o3};
    *(uint4v*)(pb + (size_t)yy*ROWB) = ov;
  }
}

// ---------------- Kernel 2: shifted Gram via MFMA, no LDS staging, no main-loop barriers ----------------
// grid: bid = (cg*2 + mh)*8 + b ; 512 blocks, 512 thr (8 waves = kq(4) x nh(2))
__global__ __launch_bounds__(512, 2) void k_corr(const unsigned char* __restrict__ pad,
                                                 float* __restrict__ out){
  __shared__ float sf[7168];
  int bid = blockIdx.x;
  int b = bid & 7;
  int r0 = bid >> 3;
  int mh = r0 & 1;
  int cg = r0 >> 1;
  int dx, d0;
  if (cg < 2){ dx = 0; d0 = cg << 2; }                 // d0 = 0, 4 (dy>=0 via symmetry)
  else { int q = cg - 2; dx = 1 + q/3; d0 = -10 + 7*(q - 3*(q/3)); }

  int tid = threadIdx.x;
  int lane = tid & 63, wvi = tid >> 6;
  int kq = wvi >> 1, nh = wvi & 1;     // kq: 32-row y strip; nh: j-half

  int rA = dx & 1;
  int sh2 = 2*(dx + rA);               // byte shift within strip; mult of 4
  int ch = lane & 15, kc = lane >> 4;
  int y0 = kq << 5;
  const unsigned char* base = pad + (size_t)b*BB;

  floatx4 acc[7];
  #pragma unroll
  for (int d = 0; d < 7; ++d) acc[d] = (floatx4)(0.f);

  for (int xi = 0; xi < 4; ++xi){
    const unsigned char* pA = base + (size_t)rA*COPYB + (size_t)(y0 + d0 + 10)*ROWB
                              + (unsigned)(xi*4096 + (mh*16 + ch)*128 + sh2 + kc*16);
    const unsigned char* pB = base + (size_t)(y0 + 10)*ROWB
                              + (unsigned)(xi*4096 + (nh*16 + ch)*128 + kc*16);
    short8 ring[8];
    #pragma unroll
    for (int w = 0; w < 7; ++w) __builtin_memcpy(&ring[w], pA + (size_t)w*ROWB, 16);
    short8 BQ[8];
    #pragma unroll
    for (int k = 0; k < 8; ++k) __builtin_memcpy(&BQ[k], pB + (size_t)k*ROWB, 16);
    #pragma unroll
    for (int yl = 0; yl < 32; ++yl){
      short8 bf = BQ[yl & 7];
      if (yl < 24) __builtin_memcpy(&BQ[yl & 7], pB + (size_t)(yl + 8)*ROWB, 16);
      if (yl < 31) __builtin_memcpy(&ring[(yl + 7) & 7], pA + (size_t)(yl + 7)*ROWB, 16);
      #pragma unroll
      for (int d = 0; d < 7; ++d)
        acc[d] = __builtin_amdgcn_mfma_f32_16x16x32_bf16(ring[(yl + d) & 7], bf, acc[d], 0, 0, 0);
    }
  }

  // ---- kq reduction via LDS tree (deterministic, no atomics) ----
  #define RIDX(d,q) ((unsigned)(((((nh*7 + (d)) << 2) + (q)) << 6) + lane))
  if (kq & 1){                          // kq 1 -> slot0, kq 3 -> slot1
    float* dst = sf + (kq >> 1)*3584;
    #pragma unroll
    for (int d = 0; d < 7; ++d)
      #pragma unroll
      for (int q = 0; q < 4; ++q) dst[RIDX(d,q)] = acc[d][q];
  }
  __syncthreads();
  if (!(kq & 1)){                       // kq0 += slot0, kq2 += slot1
    const float* src = sf + (kq >> 1)*3584;
    #pragma unroll
    for (int d = 0; d < 7; ++d)
      #pragma unroll
      for (int q = 0; q < 4; ++q) acc[d][q] += src[RIDX(d,q)];
  }
  __syncthreads();
  if (kq == 2){                         // kq2 partial -> slot0
    #pragma unroll
    for (int d = 0; d < 7; ++d)
      #pragma unroll
      for (int q = 0; q < 4; ++q) sf[RIDX(d,q)] = acc[d][q];
  }
  __syncthreads();
  if (kq == 0){
    int base_b = b * 528 * 441;
    #pragma unroll
    for (int d = 0; d < 7; ++d){
      int dy = d0 + d;
      #pragma unroll
      for (int q = 0; q < 4; ++q){
        float v = acc[d][q] + sf[RIDX(d,q)];
        int m = ((lane >> 4) << 2) + q;          // C row (M = i)
        int n = lane & 15;                        // C col (N = j)
        int i = (mh << 4) + m;
        int j = (nh << 4) + n;
        if (i <= j){
          int p = i*(65 - i)/2 + (j - i);
          out[base_b + p*441 + (10 + dy)*21 + (10 + dx)] = v;
          if (i == j && (dy != 0 || dx != 0))
            out[base_b + p*441 + (10 - dy)*21 + (10 - dx)] = v;   // autocorr symmetry
        } else {
          int p = j*(65 - j)/2 + (i - j);
          out[base_b + p*441 + (10 - dy)*21 + (10 - dx)] = v;     // pair (j,i) at (-dy,-dx)
        }
      }
    }
  }
  #undef RIDX
}

extern "C" void kernel_launch(void* const* d_in, const int* in_sizes, int n_in,
                              void* d_out, int out_size, void* d_ws, size_t ws_size,
                              hipStream_t stream){
  const float* x = (const float*)d_in[0];
  unsigned char* pad = (unsigned char*)d_ws;   // 2 copies * 19.4 MB = 38.8 MB
  float* out = (float*)d_out;
  k_std<<<dim3(256), dim3(256), 0, stream>>>(x, pad);
  k_corr<<<dim3(512), dim3(512), 0, stream>>>(pad, out);
}